// Round 1
// baseline (1154.400 us; speedup 1.0000x reference)
//
#include <hip/hip_runtime.h>

#define CH 64

using bf16x8 = __attribute__((ext_vector_type(8))) short;
using f32x4  = __attribute__((ext_vector_type(4))) float;

__device__ __forceinline__ unsigned short f2bf(float f) {
  unsigned int u = __float_as_uint(f);
  u = (u + 0x7FFFu + ((u >> 16) & 1u)) >> 16;
  return (unsigned short)u;
}

// ---- padded strides (ushort elements): +8 pad -> lane bank step 4 (2-way, free)
#define E0S 200   // K=192+8
#define S64 72    // K=64+8
#define N0S 136   // K=128+8

// ---- edge kernel LDS layout (ushort offsets) ----
#define EW0_L 0        // [64][200]  = 12800
#define EW1_L 12800    // [64][72]   = 4608
#define EW2_L 17408    // [64][72]   = 4608
#define EW_TOT 22016
#define EH0_L 22016    // + wave*3200 (16 x 200)
#define EH1_L 34816    // + wave*1152 (16 x 72)
#define E_LDS 39424    // ushorts = 78848 B -> 2 blocks/CU

// ---- node kernel LDS layout ----
#define NW0_L 0        // [64][136] = 8704
#define NW1_L 8704
#define NW2_L 13312
#define NW_TOT 17920
#define NH0_L 17920    // + wave*2176 (16 x 136)
#define NH1_L 26624    // + wave*1152
#define N_LDS 31232    // ushorts = 62464 B

// ws layout: edge weights 3*22016 ushorts @0, node weights 3*17920 @66048,
// agg (N*CH f32) @ byte 262144
#define WS_NW 66048
#define WS_AGG_BYTES 262144

// ================= weight prep: f32 -> transposed padded bf16 =================
__global__ void prep_w(const float* __restrict__ ew0, const float* __restrict__ ew1,
                       const float* __restrict__ ew2, const float* __restrict__ nw0,
                       const float* __restrict__ nw1, const float* __restrict__ nw2,
                       unsigned short* __restrict__ ws) {
  int i = blockIdx.x * 256 + threadIdx.x;
  if (i < 36864) {                       // ew0: (L,192,64)
    int l = i / 12288, r = i % 12288, k = r / 64, n = r % 64;
    ws[l * EW_TOT + EW0_L + n * E0S + k] = f2bf(ew0[i]);
  } else if (i < 49152) {                // ew1: (L,64,64)
    int j = i - 36864, l = j / 4096, r = j % 4096, k = r / 64, n = r % 64;
    ws[l * EW_TOT + EW1_L + n * S64 + k] = f2bf(ew1[j]);
  } else if (i < 61440) {                // ew2
    int j = i - 49152, l = j / 4096, r = j % 4096, k = r / 64, n = r % 64;
    ws[l * EW_TOT + EW2_L + n * S64 + k] = f2bf(ew2[j]);
  } else if (i < 86016) {                // nw0: (L,128,64)
    int j = i - 61440, l = j / 8192, r = j % 8192, k = r / 64, n = r % 64;
    ws[WS_NW + l * NW_TOT + NW0_L + n * N0S + k] = f2bf(nw0[j]);
  } else if (i < 98304) {                // nw1
    int j = i - 86016, l = j / 4096, r = j % 4096, k = r / 64, n = r % 64;
    ws[WS_NW + l * NW_TOT + NW1_L + n * S64 + k] = f2bf(nw1[j]);
  } else if (i < 110592) {               // nw2
    int j = i - 98304, l = j / 4096, r = j % 4096, k = r / 64, n = r % 64;
    ws[WS_NW + l * NW_TOT + NW2_L + n * S64 + k] = f2bf(nw2[j]);
  }
}

// ================= edge kernel =================
__global__ __launch_bounds__(256, 2)
void edge_kernel(const float* x, const float* e_in, float* e_out,
                 const int* __restrict__ src, const int* __restrict__ dst,
                 const unsigned short* __restrict__ wg,
                 const float* __restrict__ b0, const float* __restrict__ b1,
                 const float* __restrict__ b2, const float* __restrict__ gam,
                 const float* __restrict__ bet, float* agg, int nE) {
  __shared__ unsigned short lds[E_LDS];
  const int tid = threadIdx.x;
  {
    const uint4* s = (const uint4*)wg;
    uint4* d4 = (uint4*)lds;
    for (int i = tid; i < EW_TOT / 8; i += 256) d4[i] = s[i];
  }
  __syncthreads();

  const int wave = tid >> 6, lane = tid & 63;
  const int quad = lane >> 4, l15 = lane & 15;
  const int h0o = EH0_L + wave * 3200;
  const int h1o = EH1_L + wave * 1152;

  float b0c[4], b1c[4], b2c[4], gc[4], btc[4];
#pragma unroll
  for (int j = 0; j < 4; ++j) {
    int col = j * 16 + l15;
    b0c[j] = b0[col]; b1c[j] = b1[col]; b2c[j] = b2[col];
    gc[j] = gam[col]; btc[j] = bet[col];
  }

  for (int base = blockIdx.x * 64; base < nE; base += gridDim.x * 64) {
    const int ebase = base + wave * 16;
    // ---- stage h0 = bf16 cat(x[src], x[dst], e) : 16 x 192 ----
#pragma unroll
    for (int p = 0; p < 4; ++p) {
      int el = p * 4 + quad;
      int eidx = ebase + el;
      int s = src[eidx], d = dst[eidx];
      float4 vs = *(const float4*)(x + (size_t)s * CH + l15 * 4);
      float4 vd = *(const float4*)(x + (size_t)d * CH + l15 * 4);
      float4 ve = *(const float4*)(e_in + (size_t)eidx * CH + l15 * 4);
      ushort4 us; us.x = f2bf(vs.x); us.y = f2bf(vs.y); us.z = f2bf(vs.z); us.w = f2bf(vs.w);
      ushort4 ud; ud.x = f2bf(vd.x); ud.y = f2bf(vd.y); ud.z = f2bf(vd.z); ud.w = f2bf(vd.w);
      ushort4 ue; ue.x = f2bf(ve.x); ue.y = f2bf(ve.y); ue.z = f2bf(ve.z); ue.w = f2bf(ve.w);
      *(ushort4*)(lds + h0o + el * E0S + l15 * 4)       = us;
      *(ushort4*)(lds + h0o + el * E0S + 64 + l15 * 4)  = ud;
      *(ushort4*)(lds + h0o + el * E0S + 128 + l15 * 4) = ue;
    }
    // ---- stage 0: [16x192] @ [192x64] ----
    f32x4 acc0[4];
#pragma unroll
    for (int j = 0; j < 4; ++j) acc0[j] = (f32x4){0.f, 0.f, 0.f, 0.f};
#pragma unroll
    for (int t = 0; t < 6; ++t) {
      bf16x8 a = *(const bf16x8*)(lds + h0o + l15 * E0S + t * 32 + quad * 8);
#pragma unroll
      for (int j = 0; j < 4; ++j) {
        bf16x8 b = *(const bf16x8*)(lds + EW0_L + (j * 16 + l15) * E0S + t * 32 + quad * 8);
        acc0[j] = __builtin_amdgcn_mfma_f32_16x16x32_bf16(a, b, acc0[j], 0, 0, 0);
      }
    }
    // h1 = relu(acc0 + b0) -> LDS (A-layout rows)
#pragma unroll
    for (int j = 0; j < 4; ++j) {
      int col = j * 16 + l15;
#pragma unroll
      for (int r = 0; r < 4; ++r) {
        float v = fmaxf(acc0[j][r] + b0c[j], 0.f);
        lds[h1o + (quad * 4 + r) * S64 + col] = f2bf(v);
      }
    }
    // ---- stage 1: [16x64] @ [64x64] ----
    f32x4 acc1[4];
#pragma unroll
    for (int j = 0; j < 4; ++j) acc1[j] = (f32x4){0.f, 0.f, 0.f, 0.f};
#pragma unroll
    for (int t = 0; t < 2; ++t) {
      bf16x8 a = *(const bf16x8*)(lds + h1o + l15 * S64 + t * 32 + quad * 8);
#pragma unroll
      for (int j = 0; j < 4; ++j) {
        bf16x8 b = *(const bf16x8*)(lds + EW1_L + (j * 16 + l15) * S64 + t * 32 + quad * 8);
        acc1[j] = __builtin_amdgcn_mfma_f32_16x16x32_bf16(a, b, acc1[j], 0, 0, 0);
      }
    }
    // h2 = relu(acc1 + b1) -> reuse h0 region (stride S64)
#pragma unroll
    for (int j = 0; j < 4; ++j) {
      int col = j * 16 + l15;
#pragma unroll
      for (int r = 0; r < 4; ++r) {
        float v = fmaxf(acc1[j][r] + b1c[j], 0.f);
        lds[h0o + (quad * 4 + r) * S64 + col] = f2bf(v);
      }
    }
    // ---- stage 2 ----
    f32x4 acc2[4];
#pragma unroll
    for (int j = 0; j < 4; ++j) acc2[j] = (f32x4){0.f, 0.f, 0.f, 0.f};
#pragma unroll
    for (int t = 0; t < 2; ++t) {
      bf16x8 a = *(const bf16x8*)(lds + h0o + l15 * S64 + t * 32 + quad * 8);
#pragma unroll
      for (int j = 0; j < 4; ++j) {
        bf16x8 b = *(const bf16x8*)(lds + EW2_L + (j * 16 + l15) * S64 + t * 32 + quad * 8);
        acc2[j] = __builtin_amdgcn_mfma_f32_16x16x32_bf16(a, b, acc2[j], 0, 0, 0);
      }
    }
    // ---- LayerNorm + residual + scatter-add ----
    float vv[4][4], s1[4], s2[4];
#pragma unroll
    for (int r = 0; r < 4; ++r) { s1[r] = 0.f; s2[r] = 0.f; }
#pragma unroll
    for (int j = 0; j < 4; ++j)
#pragma unroll
      for (int r = 0; r < 4; ++r) {
        float v = acc2[j][r] + b2c[j];
        vv[j][r] = v; s1[r] += v; s2[r] += v * v;
      }
#pragma unroll
    for (int m = 1; m < 16; m <<= 1)
#pragma unroll
      for (int r = 0; r < 4; ++r) {
        s1[r] += __shfl_xor(s1[r], m, 64);
        s2[r] += __shfl_xor(s2[r], m, 64);
      }
#pragma unroll
    for (int r = 0; r < 4; ++r) {
      int eidx = ebase + quad * 4 + r;
      float mean = s1[r] * 0.015625f;
      float var = s2[r] * 0.015625f - mean * mean;
      float rstd = rsqrtf(var + 1e-5f);
      int dnode = dst[eidx];
      float* aggrow = agg + (size_t)dnode * CH;
      const float* ein_row = e_in + (size_t)eidx * CH;
      float* eout_row = e_out + (size_t)eidx * CH;
#pragma unroll
      for (int j = 0; j < 4; ++j) {
        int col = j * 16 + l15;
        float y = (vv[j][r] - mean) * rstd * gc[j] + btc[j];
        float out = ein_row[col] + y;
        eout_row[col] = out;
        atomicAdd(aggrow + col, out);
      }
    }
  }
}

// ================= node kernel =================
__global__ __launch_bounds__(256, 2)
void node_kernel(const float* x_in, const float* __restrict__ agg_in,
                 const unsigned short* __restrict__ wg,
                 const float* __restrict__ b0, const float* __restrict__ b1,
                 const float* __restrict__ b2, const float* __restrict__ gam,
                 const float* __restrict__ bet, float* x_out, int nN) {
  __shared__ unsigned short lds[N_LDS];
  const int tid = threadIdx.x;
  {
    const uint4* s = (const uint4*)wg;
    uint4* d4 = (uint4*)lds;
    for (int i = tid; i < NW_TOT / 8; i += 256) d4[i] = s[i];
  }
  __syncthreads();

  const int wave = tid >> 6, lane = tid & 63;
  const int quad = lane >> 4, l15 = lane & 15;
  const int nbase = (blockIdx.x * 4 + wave) * 16;
  if (nbase >= nN) return;
  const int h0o = NH0_L + wave * 2176;
  const int h1o = NH1_L + wave * 1152;

  float b0c[4], b1c[4], b2c[4], gc[4], btc[4];
#pragma unroll
  for (int j = 0; j < 4; ++j) {
    int col = j * 16 + l15;
    b0c[j] = b0[col]; b1c[j] = b1[col]; b2c[j] = b2[col];
    gc[j] = gam[col]; btc[j] = bet[col];
  }

  // stage h0 = bf16 cat(x, agg) : 16 x 128
#pragma unroll
  for (int p = 0; p < 4; ++p) {
    int nl = p * 4 + quad;
    int node = nbase + nl;
    float4 vx = *(const float4*)(x_in + (size_t)node * CH + l15 * 4);
    float4 va = *(const float4*)(agg_in + (size_t)node * CH + l15 * 4);
    ushort4 ux; ux.x = f2bf(vx.x); ux.y = f2bf(vx.y); ux.z = f2bf(vx.z); ux.w = f2bf(vx.w);
    ushort4 ua; ua.x = f2bf(va.x); ua.y = f2bf(va.y); ua.z = f2bf(va.z); ua.w = f2bf(va.w);
    *(ushort4*)(lds + h0o + nl * N0S + l15 * 4)      = ux;
    *(ushort4*)(lds + h0o + nl * N0S + 64 + l15 * 4) = ua;
  }
  f32x4 acc0[4];
#pragma unroll
  for (int j = 0; j < 4; ++j) acc0[j] = (f32x4){0.f, 0.f, 0.f, 0.f};
#pragma unroll
  for (int t = 0; t < 4; ++t) {
    bf16x8 a = *(const bf16x8*)(lds + h0o + l15 * N0S + t * 32 + quad * 8);
#pragma unroll
    for (int j = 0; j < 4; ++j) {
      bf16x8 b = *(const bf16x8*)(lds + NW0_L + (j * 16 + l15) * N0S + t * 32 + quad * 8);
      acc0[j] = __builtin_amdgcn_mfma_f32_16x16x32_bf16(a, b, acc0[j], 0, 0, 0);
    }
  }
#pragma unroll
  for (int j = 0; j < 4; ++j) {
    int col = j * 16 + l15;
#pragma unroll
    for (int r = 0; r < 4; ++r) {
      float v = fmaxf(acc0[j][r] + b0c[j], 0.f);
      lds[h1o + (quad * 4 + r) * S64 + col] = f2bf(v);
    }
  }
  f32x4 acc1[4];
#pragma unroll
  for (int j = 0; j < 4; ++j) acc1[j] = (f32x4){0.f, 0.f, 0.f, 0.f};
#pragma unroll
  for (int t = 0; t < 2; ++t) {
    bf16x8 a = *(const bf16x8*)(lds + h1o + l15 * S64 + t * 32 + quad * 8);
#pragma unroll
    for (int j = 0; j < 4; ++j) {
      bf16x8 b = *(const bf16x8*)(lds + NW1_L + (j * 16 + l15) * S64 + t * 32 + quad * 8);
      acc1[j] = __builtin_amdgcn_mfma_f32_16x16x32_bf16(a, b, acc1[j], 0, 0, 0);
    }
  }
#pragma unroll
  for (int j = 0; j < 4; ++j) {
    int col = j * 16 + l15;
#pragma unroll
    for (int r = 0; r < 4; ++r) {
      float v = fmaxf(acc1[j][r] + b1c[j], 0.f);
      lds[h0o + (quad * 4 + r) * S64 + col] = f2bf(v);
    }
  }
  f32x4 acc2[4];
#pragma unroll
  for (int j = 0; j < 4; ++j) acc2[j] = (f32x4){0.f, 0.f, 0.f, 0.f};
#pragma unroll
  for (int t = 0; t < 2; ++t) {
    bf16x8 a = *(const bf16x8*)(lds + h0o + l15 * S64 + t * 32 + quad * 8);
#pragma unroll
    for (int j = 0; j < 4; ++j) {
      bf16x8 b = *(const bf16x8*)(lds + NW2_L + (j * 16 + l15) * S64 + t * 32 + quad * 8);
      acc2[j] = __builtin_amdgcn_mfma_f32_16x16x32_bf16(a, b, acc2[j], 0, 0, 0);
    }
  }
  float vv[4][4], s1[4], s2[4];
#pragma unroll
  for (int r = 0; r < 4; ++r) { s1[r] = 0.f; s2[r] = 0.f; }
#pragma unroll
  for (int j = 0; j < 4; ++j)
#pragma unroll
    for (int r = 0; r < 4; ++r) {
      float v = acc2[j][r] + b2c[j];
      vv[j][r] = v; s1[r] += v; s2[r] += v * v;
    }
#pragma unroll
  for (int m = 1; m < 16; m <<= 1)
#pragma unroll
    for (int r = 0; r < 4; ++r) {
      s1[r] += __shfl_xor(s1[r], m, 64);
      s2[r] += __shfl_xor(s2[r], m, 64);
    }
#pragma unroll
  for (int r = 0; r < 4; ++r) {
    int node = nbase + quad * 4 + r;
    float mean = s1[r] * 0.015625f;
    float var = s2[r] * 0.015625f - mean * mean;
    float rstd = rsqrtf(var + 1e-5f);
    const float* xin_row = x_in + (size_t)node * CH;
    float* xout_row = x_out + (size_t)node * CH;
#pragma unroll
    for (int j = 0; j < 4; ++j) {
      int col = j * 16 + l15;
      float y = (vv[j][r] - mean) * rstd * gc[j] + btc[j];
      xout_row[col] = xin_row[col] + y;
    }
  }
}

// ================= launcher =================
extern "C" void kernel_launch(void* const* d_in, const int* in_sizes, int n_in,
                              void* d_out, int out_size, void* d_ws, size_t ws_size,
                              hipStream_t stream) {
  const float* x0 = (const float*)d_in[0];
  const float* e0 = (const float*)d_in[1];
  const int* ei  = (const int*)d_in[2];
  const float* ew0 = (const float*)d_in[3];
  const float* eb0 = (const float*)d_in[4];
  const float* ew1 = (const float*)d_in[5];
  const float* eb1 = (const float*)d_in[6];
  const float* ew2 = (const float*)d_in[7];
  const float* eb2 = (const float*)d_in[8];
  const float* eg  = (const float*)d_in[9];
  const float* ebt = (const float*)d_in[10];
  const float* nw0 = (const float*)d_in[11];
  const float* nb0 = (const float*)d_in[12];
  const float* nw1 = (const float*)d_in[13];
  const float* nb1 = (const float*)d_in[14];
  const float* nw2 = (const float*)d_in[15];
  const float* nb2 = (const float*)d_in[16];
  const float* ng  = (const float*)d_in[17];
  const float* nbt = (const float*)d_in[18];

  const int N = in_sizes[0] / CH;   // 50000
  const int E = in_sizes[1] / CH;   // 800000
  const int* src = ei;
  const int* dst = ei + E;

  float* xout = (float*)d_out;
  float* eout = (float*)d_out + (size_t)N * CH;

  unsigned short* wsu = (unsigned short*)d_ws;
  float* agg = (float*)((char*)d_ws + WS_AGG_BYTES);

  prep_w<<<432, 256, 0, stream>>>(ew0, ew1, ew2, nw0, nw1, nw2, wsu);

  for (int l = 0; l < 3; ++l) {
    hipMemsetAsync(agg, 0, (size_t)N * CH * sizeof(float), stream);
    const float* xin = (l == 0) ? x0 : xout;
    const float* einp = (l == 0) ? e0 : eout;
    edge_kernel<<<512, 256, 0, stream>>>(
        xin, einp, eout, src, dst, wsu + l * EW_TOT,
        eb0 + l * CH, eb1 + l * CH, eb2 + l * CH, eg + l * CH, ebt + l * CH,
        agg, E);
    node_kernel<<<(N / 16 + 3) / 4, 256, 0, stream>>>(
        xin, agg, wsu + WS_NW + l * NW_TOT,
        nb0 + l * CH, nb1 + l * CH, nb2 + l * CH, ng + l * CH, nbt + l * CH,
        xout, N);
  }
}

// Round 2
// 1131.842 us; speedup vs baseline: 1.0199x; 1.0199x over previous
//
#include <hip/hip_runtime.h>

#define CH 64

using bf16x8 = __attribute__((ext_vector_type(8))) short;
using f32x4  = __attribute__((ext_vector_type(4))) float;

__device__ __forceinline__ unsigned short f2bf(float f) {
  unsigned int u = __float_as_uint(f);
  u = (u + 0x7FFFu + ((u >> 16) & 1u)) >> 16;
  return (unsigned short)u;
}

// ---- padded strides (ushort elements)
#define E0S 200   // K=192+8
#define S64 72    // K=64+8
#define N0S 136   // K=128+8

// ---- edge kernel LDS layout (ushort offsets) ----
#define EW0_L 0        // [64][200]
#define EW1_L 12800    // [64][72]
#define EW2_L 17408    // [64][72]
#define EW_TOT 22016
#define EH0_L 22016    // + wave*3200
#define EH1_L 34816    // + wave*1152
#define E_LDS 39424    // 78848 B -> 2 blocks/CU

// ---- node kernel LDS layout ----
#define NW0_L 0
#define NW1_L 8704
#define NW2_L 13312
#define NW_TOT 17920
#define NH0_L 17920
#define NH1_L 26624
#define N_LDS 31232

// ---- ws layout (bytes) ----
// [0, 262144)            bf16 weights (edge 3*22016 + node 3*17920 ushorts)
// [262144, +12.8MB)      agg f32 N*64
// [13062144, +200064)    row_ptr int[N+1]
// [13262208, +200000)    next/counts int[N]
// [13462208, +3.2MB)     sorted edge ids int[E]
#define WS_NW 66048            // ushort offset of node weights
#define WS_AGG_B    262144
#define WS_ROWPTR_B 13062144
#define WS_NEXT_B   13262208
#define WS_EID_B    13462208

// ================= weight prep: f32 -> transposed padded bf16 =================
__global__ void prep_w(const float* __restrict__ ew0, const float* __restrict__ ew1,
                       const float* __restrict__ ew2, const float* __restrict__ nw0,
                       const float* __restrict__ nw1, const float* __restrict__ nw2,
                       unsigned short* __restrict__ ws) {
  int i = blockIdx.x * 256 + threadIdx.x;
  if (i < 36864) {                       // ew0: (L,192,64)
    int l = i / 12288, r = i % 12288, k = r / 64, n = r % 64;
    ws[l * EW_TOT + EW0_L + n * E0S + k] = f2bf(ew0[i]);
  } else if (i < 49152) {                // ew1: (L,64,64)
    int j = i - 36864, l = j / 4096, r = j % 4096, k = r / 64, n = r % 64;
    ws[l * EW_TOT + EW1_L + n * S64 + k] = f2bf(ew1[j]);
  } else if (i < 61440) {                // ew2
    int j = i - 49152, l = j / 4096, r = j % 4096, k = r / 64, n = r % 64;
    ws[l * EW_TOT + EW2_L + n * S64 + k] = f2bf(ew2[j]);
  } else if (i < 86016) {                // nw0: (L,128,64)
    int j = i - 61440, l = j / 8192, r = j % 8192, k = r / 64, n = r % 64;
    ws[WS_NW + l * NW_TOT + NW0_L + n * N0S + k] = f2bf(nw0[j]);
  } else if (i < 98304) {                // nw1
    int j = i - 86016, l = j / 4096, r = j % 4096, k = r / 64, n = r % 64;
    ws[WS_NW + l * NW_TOT + NW1_L + n * S64 + k] = f2bf(nw1[j]);
  } else if (i < 110592) {               // nw2
    int j = i - 98304, l = j / 4096, r = j % 4096, k = r / 64, n = r % 64;
    ws[WS_NW + l * NW_TOT + NW2_L + n * S64 + k] = f2bf(nw2[j]);
  }
}

// ================= CSR build =================
__global__ void hist_k(const int* __restrict__ dst, int* __restrict__ counts, int nE) {
  int i = blockIdx.x * 256 + threadIdx.x;
  if (i < nE) atomicAdd(counts + dst[i], 1);
}

// single block, 1024 threads; counts may alias `next` (each elem read then written by same thread)
__global__ void scan_k(const int* __restrict__ counts, int* __restrict__ row_ptr,
                       int* __restrict__ next, int n) {
  __shared__ int wsum[16];
  __shared__ int chunk_tot;
  __shared__ int base_sh;
  const int tid = threadIdx.x, lane = tid & 63, wv = tid >> 6;
  if (tid == 0) { base_sh = 0; row_ptr[0] = 0; }
  __syncthreads();
  for (int start = 0; start < n; start += 4096) {
    int idx = start + tid * 4;
    int v[4], s = 0;
#pragma unroll
    for (int k = 0; k < 4; ++k) { v[k] = (idx + k < n) ? counts[idx + k] : 0; s += v[k]; }
    int incl = s;
#pragma unroll
    for (int off = 1; off < 64; off <<= 1) {
      int t = __shfl_up(incl, off, 64);
      if (lane >= off) incl += t;
    }
    if (lane == 63) wsum[wv] = incl;
    __syncthreads();
    if (wv == 0 && lane < 16) {
      int w = wsum[lane];
      int wincl = w;
#pragma unroll
      for (int off = 1; off < 16; off <<= 1) {
        int t = __shfl_up(wincl, off, 16);
        if (lane >= off) wincl += t;
      }
      if (lane == 15) chunk_tot = wincl;
      wsum[lane] = wincl - w;   // exclusive over waves
    }
    __syncthreads();
    int run = base_sh + wsum[wv] + (incl - s);
#pragma unroll
    for (int k = 0; k < 4; ++k) {
      int i = idx + k;
      if (i < n) { next[i] = run; run += v[k]; row_ptr[i + 1] = run; }
    }
    __syncthreads();
    if (tid == 0) base_sh += chunk_tot;
    __syncthreads();
  }
}

__global__ void scatter_k(const int* __restrict__ dst, int* __restrict__ next,
                          int* __restrict__ eid, int nE) {
  int i = blockIdx.x * 256 + threadIdx.x;
  if (i < nE) {
    int p = atomicAdd(next + dst[i], 1);
    eid[p] = i;
  }
}

// ================= edge kernel (no atomics) =================
__global__ __launch_bounds__(256, 2)
void edge_kernel(const float* x, const float* e_in, float* e_out,
                 const int* __restrict__ src, const int* __restrict__ dst,
                 const unsigned short* __restrict__ wg,
                 const float* __restrict__ b0, const float* __restrict__ b1,
                 const float* __restrict__ b2, const float* __restrict__ gam,
                 const float* __restrict__ bet, int nE) {
  __shared__ unsigned short lds[E_LDS];
  const int tid = threadIdx.x;
  {
    const uint4* s = (const uint4*)wg;
    uint4* d4 = (uint4*)lds;
    for (int i = tid; i < EW_TOT / 8; i += 256) d4[i] = s[i];
  }
  __syncthreads();

  const int wave = tid >> 6, lane = tid & 63;
  const int quad = lane >> 4, l15 = lane & 15;
  const int h0o = EH0_L + wave * 3200;
  const int h1o = EH1_L + wave * 1152;

  float b0c[4], b1c[4], b2c[4], gc[4], btc[4];
#pragma unroll
  for (int j = 0; j < 4; ++j) {
    int col = j * 16 + l15;
    b0c[j] = b0[col]; b1c[j] = b1[col]; b2c[j] = b2[col];
    gc[j] = gam[col]; btc[j] = bet[col];
  }

  for (int base = blockIdx.x * 64; base < nE; base += gridDim.x * 64) {
    const int ebase = base + wave * 16;
    // ---- stage h0 = bf16 cat(x[src], x[dst], e) : 16 x 192 ----
#pragma unroll
    for (int p = 0; p < 4; ++p) {
      int el = p * 4 + quad;
      int eidx = ebase + el;
      int s = src[eidx], d = dst[eidx];
      float4 vs = *(const float4*)(x + (size_t)s * CH + l15 * 4);
      float4 vd = *(const float4*)(x + (size_t)d * CH + l15 * 4);
      float4 ve = *(const float4*)(e_in + (size_t)eidx * CH + l15 * 4);
      ushort4 us; us.x = f2bf(vs.x); us.y = f2bf(vs.y); us.z = f2bf(vs.z); us.w = f2bf(vs.w);
      ushort4 ud; ud.x = f2bf(vd.x); ud.y = f2bf(vd.y); ud.z = f2bf(vd.z); ud.w = f2bf(vd.w);
      ushort4 ue; ue.x = f2bf(ve.x); ue.y = f2bf(ve.y); ue.z = f2bf(ve.z); ue.w = f2bf(ve.w);
      *(ushort4*)(lds + h0o + el * E0S + l15 * 4)       = us;
      *(ushort4*)(lds + h0o + el * E0S + 64 + l15 * 4)  = ud;
      *(ushort4*)(lds + h0o + el * E0S + 128 + l15 * 4) = ue;
    }
    // ---- stage 0: [16x192] @ [192x64] ----
    f32x4 acc0[4];
#pragma unroll
    for (int j = 0; j < 4; ++j) acc0[j] = (f32x4){0.f, 0.f, 0.f, 0.f};
#pragma unroll
    for (int t = 0; t < 6; ++t) {
      bf16x8 a = *(const bf16x8*)(lds + h0o + l15 * E0S + t * 32 + quad * 8);
#pragma unroll
      for (int j = 0; j < 4; ++j) {
        bf16x8 b = *(const bf16x8*)(lds + EW0_L + (j * 16 + l15) * E0S + t * 32 + quad * 8);
        acc0[j] = __builtin_amdgcn_mfma_f32_16x16x32_bf16(a, b, acc0[j], 0, 0, 0);
      }
    }
#pragma unroll
    for (int j = 0; j < 4; ++j) {
      int col = j * 16 + l15;
#pragma unroll
      for (int r = 0; r < 4; ++r) {
        float v = fmaxf(acc0[j][r] + b0c[j], 0.f);
        lds[h1o + (quad * 4 + r) * S64 + col] = f2bf(v);
      }
    }
    // ---- stage 1 ----
    f32x4 acc1[4];
#pragma unroll
    for (int j = 0; j < 4; ++j) acc1[j] = (f32x4){0.f, 0.f, 0.f, 0.f};
#pragma unroll
    for (int t = 0; t < 2; ++t) {
      bf16x8 a = *(const bf16x8*)(lds + h1o + l15 * S64 + t * 32 + quad * 8);
#pragma unroll
      for (int j = 0; j < 4; ++j) {
        bf16x8 b = *(const bf16x8*)(lds + EW1_L + (j * 16 + l15) * S64 + t * 32 + quad * 8);
        acc1[j] = __builtin_amdgcn_mfma_f32_16x16x32_bf16(a, b, acc1[j], 0, 0, 0);
      }
    }
#pragma unroll
    for (int j = 0; j < 4; ++j) {
      int col = j * 16 + l15;
#pragma unroll
      for (int r = 0; r < 4; ++r) {
        float v = fmaxf(acc1[j][r] + b1c[j], 0.f);
        lds[h0o + (quad * 4 + r) * S64 + col] = f2bf(v);
      }
    }
    // ---- stage 2 ----
    f32x4 acc2[4];
#pragma unroll
    for (int j = 0; j < 4; ++j) acc2[j] = (f32x4){0.f, 0.f, 0.f, 0.f};
#pragma unroll
    for (int t = 0; t < 2; ++t) {
      bf16x8 a = *(const bf16x8*)(lds + h0o + l15 * S64 + t * 32 + quad * 8);
#pragma unroll
      for (int j = 0; j < 4; ++j) {
        bf16x8 b = *(const bf16x8*)(lds + EW2_L + (j * 16 + l15) * S64 + t * 32 + quad * 8);
        acc2[j] = __builtin_amdgcn_mfma_f32_16x16x32_bf16(a, b, acc2[j], 0, 0, 0);
      }
    }
    // ---- LayerNorm + residual ----
    float vv[4][4], s1[4], s2[4];
#pragma unroll
    for (int r = 0; r < 4; ++r) { s1[r] = 0.f; s2[r] = 0.f; }
#pragma unroll
    for (int j = 0; j < 4; ++j)
#pragma unroll
      for (int r = 0; r < 4; ++r) {
        float v = acc2[j][r] + b2c[j];
        vv[j][r] = v; s1[r] += v; s2[r] += v * v;
      }
#pragma unroll
    for (int m = 1; m < 16; m <<= 1)
#pragma unroll
      for (int r = 0; r < 4; ++r) {
        s1[r] += __shfl_xor(s1[r], m, 64);
        s2[r] += __shfl_xor(s2[r], m, 64);
      }
#pragma unroll
    for (int r = 0; r < 4; ++r) {
      int eidx = ebase + quad * 4 + r;
      float mean = s1[r] * 0.015625f;
      float var = s2[r] * 0.015625f - mean * mean;
      float rstd = rsqrtf(var + 1e-5f);
      const float* ein_row = e_in + (size_t)eidx * CH;
      float* eout_row = e_out + (size_t)eidx * CH;
#pragma unroll
      for (int j = 0; j < 4; ++j) {
        int col = j * 16 + l15;
        float y = (vv[j][r] - mean) * rstd * gc[j] + btc[j];
        eout_row[col] = ein_row[col] + y;
      }
    }
  }
}

// ================= gather aggregation (CSR) =================
__global__ __launch_bounds__(256)
void agg_kernel(const float* __restrict__ e, const int* __restrict__ row_ptr,
                const int* __restrict__ eid, float* __restrict__ agg, int nN) {
  int node = blockIdx.x * 4 + (threadIdx.x >> 6);
  int lane = threadIdx.x & 63;
  if (node >= nN) return;
  int r0 = row_ptr[node], r1 = row_ptr[node + 1];
  float s0 = 0.f, s1 = 0.f, s2 = 0.f, s3 = 0.f;
  int i = r0;
  for (; i + 4 <= r1; i += 4) {
    int e0 = eid[i], e1 = eid[i + 1], e2 = eid[i + 2], e3 = eid[i + 3];
    s0 += e[(size_t)e0 * CH + lane];
    s1 += e[(size_t)e1 * CH + lane];
    s2 += e[(size_t)e2 * CH + lane];
    s3 += e[(size_t)e3 * CH + lane];
  }
  for (; i < r1; ++i) s0 += e[(size_t)eid[i] * CH + lane];
  agg[(size_t)node * CH + lane] = (s0 + s1) + (s2 + s3);
}

// ================= node kernel =================
__global__ __launch_bounds__(256, 2)
void node_kernel(const float* x_in, const float* __restrict__ agg_in,
                 const unsigned short* __restrict__ wg,
                 const float* __restrict__ b0, const float* __restrict__ b1,
                 const float* __restrict__ b2, const float* __restrict__ gam,
                 const float* __restrict__ bet, float* x_out, int nN) {
  __shared__ unsigned short lds[N_LDS];
  const int tid = threadIdx.x;
  {
    const uint4* s = (const uint4*)wg;
    uint4* d4 = (uint4*)lds;
    for (int i = tid; i < NW_TOT / 8; i += 256) d4[i] = s[i];
  }
  __syncthreads();

  const int wave = tid >> 6, lane = tid & 63;
  const int quad = lane >> 4, l15 = lane & 15;
  const int nbase = (blockIdx.x * 4 + wave) * 16;
  if (nbase >= nN) return;
  const int h0o = NH0_L + wave * 2176;
  const int h1o = NH1_L + wave * 1152;

  float b0c[4], b1c[4], b2c[4], gc[4], btc[4];
#pragma unroll
  for (int j = 0; j < 4; ++j) {
    int col = j * 16 + l15;
    b0c[j] = b0[col]; b1c[j] = b1[col]; b2c[j] = b2[col];
    gc[j] = gam[col]; btc[j] = bet[col];
  }

#pragma unroll
  for (int p = 0; p < 4; ++p) {
    int nl = p * 4 + quad;
    int node = nbase + nl;
    float4 vx = *(const float4*)(x_in + (size_t)node * CH + l15 * 4);
    float4 va = *(const float4*)(agg_in + (size_t)node * CH + l15 * 4);
    ushort4 ux; ux.x = f2bf(vx.x); ux.y = f2bf(vx.y); ux.z = f2bf(vx.z); ux.w = f2bf(vx.w);
    ushort4 ua; ua.x = f2bf(va.x); ua.y = f2bf(va.y); ua.z = f2bf(va.z); ua.w = f2bf(va.w);
    *(ushort4*)(lds + h0o + nl * N0S + l15 * 4)      = ux;
    *(ushort4*)(lds + h0o + nl * N0S + 64 + l15 * 4) = ua;
  }
  f32x4 acc0[4];
#pragma unroll
  for (int j = 0; j < 4; ++j) acc0[j] = (f32x4){0.f, 0.f, 0.f, 0.f};
#pragma unroll
  for (int t = 0; t < 4; ++t) {
    bf16x8 a = *(const bf16x8*)(lds + h0o + l15 * N0S + t * 32 + quad * 8);
#pragma unroll
    for (int j = 0; j < 4; ++j) {
      bf16x8 b = *(const bf16x8*)(lds + NW0_L + (j * 16 + l15) * N0S + t * 32 + quad * 8);
      acc0[j] = __builtin_amdgcn_mfma_f32_16x16x32_bf16(a, b, acc0[j], 0, 0, 0);
    }
  }
#pragma unroll
  for (int j = 0; j < 4; ++j) {
    int col = j * 16 + l15;
#pragma unroll
    for (int r = 0; r < 4; ++r) {
      float v = fmaxf(acc0[j][r] + b0c[j], 0.f);
      lds[h1o + (quad * 4 + r) * S64 + col] = f2bf(v);
    }
  }
  f32x4 acc1[4];
#pragma unroll
  for (int j = 0; j < 4; ++j) acc1[j] = (f32x4){0.f, 0.f, 0.f, 0.f};
#pragma unroll
  for (int t = 0; t < 2; ++t) {
    bf16x8 a = *(const bf16x8*)(lds + h1o + l15 * S64 + t * 32 + quad * 8);
#pragma unroll
    for (int j = 0; j < 4; ++j) {
      bf16x8 b = *(const bf16x8*)(lds + NW1_L + (j * 16 + l15) * S64 + t * 32 + quad * 8);
      acc1[j] = __builtin_amdgcn_mfma_f32_16x16x32_bf16(a, b, acc1[j], 0, 0, 0);
    }
  }
#pragma unroll
  for (int j = 0; j < 4; ++j) {
    int col = j * 16 + l15;
#pragma unroll
    for (int r = 0; r < 4; ++r) {
      float v = fmaxf(acc1[j][r] + b1c[j], 0.f);
      lds[h0o + (quad * 4 + r) * S64 + col] = f2bf(v);
    }
  }
  f32x4 acc2[4];
#pragma unroll
  for (int j = 0; j < 4; ++j) acc2[j] = (f32x4){0.f, 0.f, 0.f, 0.f};
#pragma unroll
  for (int t = 0; t < 2; ++t) {
    bf16x8 a = *(const bf16x8*)(lds + h0o + l15 * S64 + t * 32 + quad * 8);
#pragma unroll
    for (int j = 0; j < 4; ++j) {
      bf16x8 b = *(const bf16x8*)(lds + NW2_L + (j * 16 + l15) * S64 + t * 32 + quad * 8);
      acc2[j] = __builtin_amdgcn_mfma_f32_16x16x32_bf16(a, b, acc2[j], 0, 0, 0);
    }
  }
  float vv[4][4], s1[4], s2[4];
#pragma unroll
  for (int r = 0; r < 4; ++r) { s1[r] = 0.f; s2[r] = 0.f; }
#pragma unroll
  for (int j = 0; j < 4; ++j)
#pragma unroll
    for (int r = 0; r < 4; ++r) {
      float v = acc2[j][r] + b2c[j];
      vv[j][r] = v; s1[r] += v; s2[r] += v * v;
    }
#pragma unroll
  for (int m = 1; m < 16; m <<= 1)
#pragma unroll
    for (int r = 0; r < 4; ++r) {
      s1[r] += __shfl_xor(s1[r], m, 64);
      s2[r] += __shfl_xor(s2[r], m, 64);
    }
#pragma unroll
  for (int r = 0; r < 4; ++r) {
    int node = nbase + quad * 4 + r;
    float mean = s1[r] * 0.015625f;
    float var = s2[r] * 0.015625f - mean * mean;
    float rstd = rsqrtf(var + 1e-5f);
    const float* xin_row = x_in + (size_t)node * CH;
    float* xout_row = x_out + (size_t)node * CH;
#pragma unroll
    for (int j = 0; j < 4; ++j) {
      int col = j * 16 + l15;
      float y = (vv[j][r] - mean) * rstd * gc[j] + btc[j];
      xout_row[col] = xin_row[col] + y;
    }
  }
}

// ================= launcher =================
extern "C" void kernel_launch(void* const* d_in, const int* in_sizes, int n_in,
                              void* d_out, int out_size, void* d_ws, size_t ws_size,
                              hipStream_t stream) {
  const float* x0 = (const float*)d_in[0];
  const float* e0 = (const float*)d_in[1];
  const int* ei  = (const int*)d_in[2];
  const float* ew0 = (const float*)d_in[3];
  const float* eb0 = (const float*)d_in[4];
  const float* ew1 = (const float*)d_in[5];
  const float* eb1 = (const float*)d_in[6];
  const float* ew2 = (const float*)d_in[7];
  const float* eb2 = (const float*)d_in[8];
  const float* eg  = (const float*)d_in[9];
  const float* ebt = (const float*)d_in[10];
  const float* nw0 = (const float*)d_in[11];
  const float* nb0 = (const float*)d_in[12];
  const float* nw1 = (const float*)d_in[13];
  const float* nb1 = (const float*)d_in[14];
  const float* nw2 = (const float*)d_in[15];
  const float* nb2 = (const float*)d_in[16];
  const float* ng  = (const float*)d_in[17];
  const float* nbt = (const float*)d_in[18];

  const int N = in_sizes[0] / CH;   // 50000
  const int E = in_sizes[1] / CH;   // 800000
  const int* src = ei;
  const int* dst = ei + E;

  float* xout = (float*)d_out;
  float* eout = (float*)d_out + (size_t)N * CH;

  unsigned short* wsu = (unsigned short*)d_ws;
  float* agg    = (float*)((char*)d_ws + WS_AGG_B);
  int* row_ptr  = (int*)((char*)d_ws + WS_ROWPTR_B);
  int* nxt      = (int*)((char*)d_ws + WS_NEXT_B);
  int* eid      = (int*)((char*)d_ws + WS_EID_B);

  prep_w<<<432, 256, 0, stream>>>(ew0, ew1, ew2, nw0, nw1, nw2, wsu);

  // CSR build (dst is constant across layers)
  hipMemsetAsync(nxt, 0, (size_t)N * sizeof(int), stream);
  hist_k<<<(E + 255) / 256, 256, 0, stream>>>(dst, nxt, E);
  scan_k<<<1, 1024, 0, stream>>>(nxt, row_ptr, nxt, N);
  scatter_k<<<(E + 255) / 256, 256, 0, stream>>>(dst, nxt, eid, E);

  for (int l = 0; l < 3; ++l) {
    const float* xin = (l == 0) ? x0 : xout;
    const float* einp = (l == 0) ? e0 : eout;
    edge_kernel<<<512, 256, 0, stream>>>(
        xin, einp, eout, src, dst, wsu + l * EW_TOT,
        eb0 + l * CH, eb1 + l * CH, eb2 + l * CH, eg + l * CH, ebt + l * CH, E);
    agg_kernel<<<(N + 3) / 4, 256, 0, stream>>>(eout, row_ptr, eid, agg, N);
    node_kernel<<<(N / 16 + 3) / 4, 256, 0, stream>>>(
        xin, agg, wsu + WS_NW + l * NW_TOT,
        nb0 + l * CH, nb1 + l * CH, nb2 + l * CH, ng + l * CH, nbt + l * CH,
        xout, N);
  }
}